// Round 3
// baseline (556.508 us; speedup 1.0000x reference)
//
#include <hip/hip_runtime.h>
#include <math.h>

typedef unsigned short u16;
typedef short s16x8 __attribute__((ext_vector_type(8)));
typedef short s16x4 __attribute__((ext_vector_type(4)));
typedef unsigned int u32x4 __attribute__((ext_vector_type(4)));
typedef __bf16 bf16x8 __attribute__((ext_vector_type(8)));
typedef float f32x4 __attribute__((ext_vector_type(4)));
typedef unsigned short u16x2 __attribute__((ext_vector_type(2)));

__device__ __forceinline__ float bf2f(u16 u) {
  unsigned x = ((unsigned)u) << 16;
  return __builtin_bit_cast(float, x);
}
__device__ __forceinline__ u16 f2bf(float f) {
  unsigned x = __builtin_bit_cast(unsigned, f);
  unsigned r = (x + 0x7FFFu + ((x >> 16) & 1u)) >> 16;
  return (u16)r;
}

// ---- MFMA wrapper robust to builtin signature (short8 vs bf16x8) ----
template <typename T>
__device__ __forceinline__ auto mfma_try(T a, T b, f32x4 c, int)
    -> decltype(__builtin_amdgcn_mfma_f32_16x16x32_bf16(a, b, c, 0, 0, 0)) {
  return __builtin_amdgcn_mfma_f32_16x16x32_bf16(a, b, c, 0, 0, 0);
}
template <typename T>
__device__ __forceinline__ f32x4 mfma_try(T a, T b, f32x4 c, long) {
  return __builtin_amdgcn_mfma_f32_16x16x32_bf16(
      __builtin_bit_cast(bf16x8, a), __builtin_bit_cast(bf16x8, b), c, 0, 0, 0);
}
__device__ __forceinline__ f32x4 mfma16x16x32(s16x8 a, s16x8 b, f32x4 c) {
  return mfma_try(a, b, c, 0);
}

// ---- async global->LDS, 16B per lane, wave-uniform LDS base + lane*16 ----
__device__ __forceinline__ void gload_lds16(const u16* g, u16* l) {
  __builtin_amdgcn_global_load_lds(
      (__attribute__((address_space(1))) void*)(u16*)g,
      (__attribute__((address_space(3))) void*)l, 16, 0, 0);
}

// ---------------- K0: pack weights to bf16 [k/8][n][8], build rowmaps ----------------
__global__ __launch_bounds__(256) void pack_kernel(
    const float* __restrict__ w1, const float* __restrict__ w2,
    const float* __restrict__ fpw, const int* __restrict__ idx1,
    const int* __restrict__ idx2, u16* __restrict__ w1p, u16* __restrict__ w2p,
    u16* __restrict__ fpwp, int* __restrict__ rm1, int* __restrict__ rm2) {
  const int T1 = 589824;           // w1 (384x1536)
  const int T2 = T1 + 589824;      // w2 (1536x384)
  const int T3 = T2 + 147456;      // fp_w (384x384)
  const int T4 = T3 + 50176;       // rowmap1
  const int T5 = T4 + 50176;       // rowmap2
  int stride = gridDim.x * 256;
  for (int i = blockIdx.x * 256 + threadIdx.x; i < T5; i += stride) {
    if (i < T1) {
      int k = i / 1536, n = i - k * 1536;
      w1p[((size_t)(k >> 3) * 1536 + n) * 8 + (k & 7)] = f2bf(w1[i]);
    } else if (i < T2) {
      int t = i - T1;
      int k = t / 384, n = t - k * 384;
      w2p[((size_t)(k >> 3) * 384 + n) * 8 + (k & 7)] = f2bf(w2[t]);
    } else if (i < T3) {
      int t = i - T2;
      int k = t / 384, n = t - k * 384;
      fpwp[((size_t)(k >> 3) * 384 + n) * 8 + (k & 7)] = f2bf(fpw[t]);
    } else if (i < T4) {
      int g = i - T3;
      rm1[g] = (g / 392) * 784 + idx1[g];
    } else {
      int g = i - T4;
      rm2[g] = (g / 392) * 784 + idx2[g];
    }
  }
}

// ---------------- K1: depthwise 7x7 conv + bias -> t (B,N,C) bf16 ----------------
__global__ __launch_bounds__(256) void dwconv_kernel(
    const float* __restrict__ x, const float* __restrict__ dww,
    const float* __restrict__ dwb, u16* __restrict__ t) {
  __shared__ __align__(16) u16 plane[8 * 34 * 40];  // 21760 B
  int tid = threadIdx.x;
  int b = blockIdx.y, c0 = blockIdx.x * 8;
  int ch = tid & 7, row = tid >> 3;
  int c = c0 + ch;

  float wg[49];
#pragma unroll
  for (int k2 = 0; k2 < 49; ++k2) wg[k2] = dww[c * 49 + k2];
  float bias = dwb[c];

  for (int q = tid; q < 1360; q += 256) {
    s16x8 z = {0, 0, 0, 0, 0, 0, 0, 0};
    *(s16x8*)(&plane[q * 8]) = z;
  }
  __syncthreads();
  for (int q = tid; q < 1568; q += 256) {
    int cc = q / 196, seg = q - cc * 196;
    int i = seg / 7, j4 = seg - i * 7;
    const float4 v = *(const float4*)(x + ((size_t)(b * 384 + c0 + cc)) * 784 +
                                      i * 28 + j4 * 4);
    s16x4 p;
    p[0] = (short)f2bf(v.x);
    p[1] = (short)f2bf(v.y);
    p[2] = (short)f2bf(v.z);
    p[3] = (short)f2bf(v.w);
    *(s16x4*)(&plane[cc * 1360 + (3 + i) * 40 + 4 + j4 * 4]) = p;
  }
  __syncthreads();

  if (row < 28) {
    float acc[28];
#pragma unroll
    for (int o = 0; o < 28; ++o) acc[o] = bias;
#pragma unroll
    for (int di = 0; di < 7; ++di) {
      const u16* base = &plane[ch * 1360 + (row + di) * 40];
      u32x4 ga = *(const u32x4*)(base);
      u32x4 gb = *(const u32x4*)(base + 8);
      u32x4 gc = *(const u32x4*)(base + 16);
      u32x4 gd = *(const u32x4*)(base + 24);
      u32x4 ge = *(const u32x4*)(base + 32);
      unsigned dw[20] = {ga[0], ga[1], ga[2], ga[3], gb[0], gb[1], gb[2],
                         gb[3], gc[0], gc[1], gc[2], gc[3], gd[0], gd[1],
                         gd[2], gd[3], ge[0], ge[1], ge[2], ge[3]};
      float v[35];
#pragma unroll
      for (int tt = 0; tt < 35; ++tt) {
        unsigned d = dw[tt >> 1];
        v[tt] = (tt & 1) ? __builtin_bit_cast(float, d & 0xFFFF0000u)
                         : __builtin_bit_cast(float, d << 16);
      }
#pragma unroll
      for (int o = 0; o < 28; ++o)
#pragma unroll
        for (int dj = 0; dj < 7; ++dj)
          acc[o] += v[o + 1 + dj] * wg[di * 7 + dj];
    }
    size_t obase = ((size_t)(b * 784 + row * 28)) * 384 + c;
#pragma unroll
    for (int o = 0; o < 28; ++o) t[obase + (size_t)o * 384] = f2bf(acc[o]);
  }
}

// ---------------- K2: gather + LayerNorm -> A1, A2 (bf16, MxK dense) ----------------
__global__ __launch_bounds__(256) void gatherln_kernel(
    const u16* __restrict__ t, const int* __restrict__ idx1,
    const int* __restrict__ idx2, const float* __restrict__ nw1,
    const float* __restrict__ nb1, const float* __restrict__ nw2,
    const float* __restrict__ nb2, u16* __restrict__ A1, u16* __restrict__ A2) {
  int wid = threadIdx.x >> 6, lane = threadIdx.x & 63;
  int g = blockIdx.x * 4 + wid;
  bool is1 = g < 50176;
  int gg = is1 ? g : g - 50176;
  const int* idx = is1 ? idx1 : idx2;
  int b = gg / 392;
  int jj = gg - b * 392;
  int ntok = idx[b * 392 + jj];
  const u16* src = t + ((size_t)(b * 784 + ntok)) * 384 + lane * 6;
  float v[6];
  u16x2 u0 = *(const u16x2*)(src);
  u16x2 u1 = *(const u16x2*)(src + 2);
  u16x2 u2 = *(const u16x2*)(src + 4);
  v[0] = bf2f(u0[0]); v[1] = bf2f(u0[1]);
  v[2] = bf2f(u1[0]); v[3] = bf2f(u1[1]);
  v[4] = bf2f(u2[0]); v[5] = bf2f(u2[1]);
  float s = 0.f, q = 0.f;
#pragma unroll
  for (int e = 0; e < 6; ++e) { s += v[e]; q += v[e] * v[e]; }
#pragma unroll
  for (int off = 32; off >= 1; off >>= 1) {
    s += __shfl_xor(s, off);
    q += __shfl_xor(q, off);
  }
  float mu = s * (1.f / 384.f);
  float var = q * (1.f / 384.f) - mu * mu;
  float rs = rsqrtf(var + 1e-6f);
  const float* nw = is1 ? nw1 : nw2;
  const float* nb = is1 ? nb1 : nb2;
  u16* dst = (is1 ? A1 : A2) + (size_t)gg * 384 + lane * 6;
  int k0 = lane * 6;
#pragma unroll
  for (int e = 0; e < 6; ++e)
    dst[e] = f2bf((v[e] - mu) * rs * nw[k0 + e] + nb[k0 + e]);
}

// ---------------- K3/K4/K5: bf16 MFMA GEMM, 128x128 tile, 4 waves ----------------
// A: M x K row-major bf16.  Wp: packed B, [k/8][n][8] bf16.
// Staging via global_load_lds (16B/lane, wave-linear dest == [kg][row][8]).
// 1-D grid (must be divisible by 8) + bijective chunked XCD swizzle.
// EPI 0: out[m*N+col] = bf16(gelu(acc + bias[col]))
// EPI 1: out[rowmap[m]*384+col] = bf16((acc + bias[col]) * scale[col])
template <int EPI>
__global__ __launch_bounds__(256) void gemm_kernel(
    const u16* __restrict__ A, const u16* __restrict__ Wp,
    const float* __restrict__ bias, const float* __restrict__ scale,
    const int* __restrict__ rowmap, u16* __restrict__ out, int N, int K,
    int gx) {
  __shared__ __align__(16) u16 As[4096];  // [kg 4][row 128][e 8]
  __shared__ __align__(16) u16 Bs[4096];  // [kg 4][col 128][e 8]
  int tid = threadIdx.x;
  int wid = tid >> 6, lane = tid & 63;
  int wm = wid >> 1, wn = wid & 1;
  // XCD swizzle: consecutive wgid (sharing an A-panel) stay on one XCD
  int nwg = gridDim.x;
  int bid = blockIdx.x;
  int wgid = (bid & 7) * (nwg >> 3) + (bid >> 3);
  int by = wgid / gx, bx = wgid - by * gx;
  int m_base = by * 128, n_base = bx * 128;
  const f32x4 vzero = {0.f, 0.f, 0.f, 0.f};
  f32x4 acc[4][4];
#pragma unroll
  for (int i = 0; i < 4; ++i)
#pragma unroll
    for (int j = 0; j < 4; ++j) acc[i][j] = vzero;
  int nk = K >> 5;
  for (int kt = 0; kt < nk; ++kt) {
#pragma unroll
    for (int it = 0; it < 2; ++it) {  // A: chunks p = wid*128+it*64+lane
      int p = wid * 128 + it * 64 + lane;
      int kg = p >> 7, row = p & 127;
      const u16* ga = A + (size_t)(m_base + row) * K + (kt << 5) + (kg << 3);
      gload_lds16(ga, &As[(wid * 128 + it * 64) * 8]);
    }
#pragma unroll
    for (int it = 0; it < 2; ++it) {  // B: chunks p -> (kg, col), coalesced
      int p = wid * 128 + it * 64 + lane;
      int kg = p >> 7, col = p & 127;
      const u16* gb = Wp + ((size_t)((kt << 2) + kg) * N + n_base + col) * 8;
      gload_lds16(gb, &Bs[(wid * 128 + it * 64) * 8]);
    }
    __syncthreads();
    int kg = lane >> 4, r = lane & 15;
    s16x8 af[4], bfr[4];
#pragma unroll
    for (int i = 0; i < 4; ++i)
      af[i] = *(const s16x8*)(&As[(kg * 128 + wm * 64 + i * 16 + r) * 8]);
#pragma unroll
    for (int j = 0; j < 4; ++j)
      bfr[j] = *(const s16x8*)(&Bs[(kg * 128 + wn * 64 + j * 16 + r) * 8]);
#pragma unroll
    for (int i = 0; i < 4; ++i)
#pragma unroll
      for (int j = 0; j < 4; ++j)
        acc[i][j] = mfma16x16x32(af[i], bfr[j], acc[i][j]);
    __syncthreads();
  }
  // epilogue: D row = (lane>>4)*4 + reg, col = lane&15
  int cl = lane & 15;
  int rg = (lane >> 4) * 4;
#pragma unroll
  for (int i = 0; i < 4; ++i) {
#pragma unroll
    for (int reg = 0; reg < 4; ++reg) {
      int m = m_base + wm * 64 + i * 16 + rg + reg;
      size_t rowoff;
      if (EPI == 0) rowoff = (size_t)m * N;
      else rowoff = (size_t)rowmap[m] * 384;
#pragma unroll
      for (int j = 0; j < 4; ++j) {
        int col = n_base + wn * 64 + j * 16 + cl;
        float v = acc[i][j][reg];
        v += bias[col];
        if (EPI == 0) v = 0.5f * v * (1.f + erff(v * 0.70710678118f));
        else v *= scale[col];
        out[rowoff + col] = f2bf(v);
      }
    }
  }
}

// ---------------- K6: un-transpose (B,N,C)->(B,C,N) + residual add ----------------
__global__ __launch_bounds__(256) void unscatter_add_kernel(
    const u16* __restrict__ U, const float* __restrict__ x,
    float* __restrict__ out) {
  __shared__ float tile[32][33];
  int b = blockIdx.y;
  int ct = blockIdx.x % 12, nt = blockIdx.x / 12;
  int c0 = ct * 32, n0 = nt * 32;
  int tid = threadIdx.x;
#pragma unroll
  for (int it = 0; it < 4; ++it) {
    int q = tid + it * 256;
    int nl = q >> 5, cl = q & 31;
    if (n0 + nl < 784)
      tile[nl][cl] = bf2f(U[((size_t)(b * 784 + n0 + nl)) * 384 + c0 + cl]);
  }
  __syncthreads();
#pragma unroll
  for (int it = 0; it < 4; ++it) {
    int q = tid + it * 256;
    int cl = q >> 5, nl = q & 31;
    int n = n0 + nl;
    if (n < 784) {
      size_t o = ((size_t)(b * 384 + c0 + cl)) * 784 + n;
      out[o] = x[o] + tile[nl][cl];
    }
  }
}

extern "C" void kernel_launch(void* const* d_in, const int* in_sizes, int n_in,
                              void* d_out, int out_size, void* d_ws,
                              size_t ws_size, hipStream_t stream) {
  const float* x = (const float*)d_in[0];
  const int* idx1 = (const int*)d_in[1];
  const int* idx2 = (const int*)d_in[2];
  const float* dww = (const float*)d_in[3];
  const float* dwb = (const float*)d_in[4];
  const float* nw = (const float*)d_in[5];
  const float* nb = (const float*)d_in[6];
  const float* w1 = (const float*)d_in[7];
  const float* b1 = (const float*)d_in[8];
  const float* w2 = (const float*)d_in[9];
  const float* b2 = (const float*)d_in[10];
  const float* gamma = (const float*)d_in[11];
  const float* fnw = (const float*)d_in[12];
  const float* fnb = (const float*)d_in[13];
  const float* fpw = (const float*)d_in[14];
  const float* fpb = (const float*)d_in[15];
  const float* fpg = (const float*)d_in[16];

  char* ws = (char*)d_ws;
  u16* H = (u16*)(ws);                     // 154,140,672 B (50176x1536)
  u16* t = (u16*)(ws);                     //  77,070,336 B (100352x384), aliases H
  u16* A1 = (u16*)(ws + 154140672);        //  38,535,168 B (50176x384)
  u16* A2 = (u16*)(ws + 192675840);        //  38,535,168 B
  u16* U = (u16*)(ws + 231211008);         //  77,070,336 B (100352x384)
  u16* w1p = (u16*)(ws + 308281344);       //   1,179,648 B
  u16* w2p = (u16*)(ws + 309460992);       //   1,179,648 B
  u16* fpwp = (u16*)(ws + 310640640);      //     294,912 B
  int* rm1 = (int*)(ws + 310935552);       //     200,704 B
  int* rm2 = (int*)(ws + 311136256);       //     200,704 B
  (void)ws_size; (void)in_sizes; (void)n_in; (void)out_size;

  pack_kernel<<<1024, 256, 0, stream>>>(w1, w2, fpw, idx1, idx2, w1p, w2p,
                                        fpwp, rm1, rm2);
  dwconv_kernel<<<dim3(48, 128), 256, 0, stream>>>(x, dww, dwb, t);
  gatherln_kernel<<<25088, 256, 0, stream>>>(t, idx1, idx2, nw, nb, fnw, fnb,
                                             A1, A2);
  gemm_kernel<0><<<4704, 256, 0, stream>>>(A1, w1p, b1, nullptr, nullptr, H,
                                           1536, 384, 12);
  gemm_kernel<1><<<1176, 256, 0, stream>>>(H, w2p, b2, gamma, rm1, U, 384,
                                           1536, 3);
  gemm_kernel<1><<<1176, 256, 0, stream>>>(A2, fpwp, fpb, fpg, rm2, U, 384,
                                           384, 3);
  unscatter_add_kernel<<<dim3(300, 128), 256, 0, stream>>>(U, x,
                                                           (float*)d_out);
}

// Round 4
// 515.862 us; speedup vs baseline: 1.0788x; 1.0788x over previous
//
#include <hip/hip_runtime.h>
#include <math.h>

typedef unsigned short u16;
typedef short s16x8 __attribute__((ext_vector_type(8)));
typedef short s16x4 __attribute__((ext_vector_type(4)));
typedef unsigned int u32x4 __attribute__((ext_vector_type(4)));
typedef __bf16 bf16x8 __attribute__((ext_vector_type(8)));
typedef float f32x4 __attribute__((ext_vector_type(4)));
typedef unsigned short u16x2 __attribute__((ext_vector_type(2)));

__device__ __forceinline__ float bf2f(u16 u) {
  unsigned x = ((unsigned)u) << 16;
  return __builtin_bit_cast(float, x);
}
__device__ __forceinline__ u16 f2bf(float f) {
  unsigned x = __builtin_bit_cast(unsigned, f);
  unsigned r = (x + 0x7FFFu + ((x >> 16) & 1u)) >> 16;
  return (u16)r;
}

// ---- MFMA wrapper robust to builtin signature (short8 vs bf16x8) ----
template <typename T>
__device__ __forceinline__ auto mfma_try(T a, T b, f32x4 c, int)
    -> decltype(__builtin_amdgcn_mfma_f32_16x16x32_bf16(a, b, c, 0, 0, 0)) {
  return __builtin_amdgcn_mfma_f32_16x16x32_bf16(a, b, c, 0, 0, 0);
}
template <typename T>
__device__ __forceinline__ f32x4 mfma_try(T a, T b, f32x4 c, long) {
  return __builtin_amdgcn_mfma_f32_16x16x32_bf16(
      __builtin_bit_cast(bf16x8, a), __builtin_bit_cast(bf16x8, b), c, 0, 0, 0);
}
__device__ __forceinline__ f32x4 mfma16x16x32(s16x8 a, s16x8 b, f32x4 c) {
  return mfma_try(a, b, c, 0);
}

// ---- async global->LDS, 16B per lane, wave-uniform LDS base + lane*16 ----
__device__ __forceinline__ void gload_lds16(const u16* g, u16* l) {
  __builtin_amdgcn_global_load_lds(
      (__attribute__((address_space(1))) void*)(u16*)g,
      (__attribute__((address_space(3))) void*)l, 16, 0, 0);
}

// ---------------- K0: pack weights to bf16 [k/8][n][8], build rowmaps ----------------
__global__ __launch_bounds__(256) void pack_kernel(
    const float* __restrict__ w1, const float* __restrict__ w2,
    const float* __restrict__ fpw, const int* __restrict__ idx1,
    const int* __restrict__ idx2, u16* __restrict__ w1p, u16* __restrict__ w2p,
    u16* __restrict__ fpwp, int* __restrict__ rm1, int* __restrict__ rm2) {
  const int T1 = 589824;           // w1 (384x1536)
  const int T2 = T1 + 589824;      // w2 (1536x384)
  const int T3 = T2 + 147456;      // fp_w (384x384)
  const int T4 = T3 + 50176;       // rowmap1
  const int T5 = T4 + 50176;       // rowmap2
  int stride = gridDim.x * 256;
  for (int i = blockIdx.x * 256 + threadIdx.x; i < T5; i += stride) {
    if (i < T1) {
      int k = i / 1536, n = i - k * 1536;
      w1p[((size_t)(k >> 3) * 1536 + n) * 8 + (k & 7)] = f2bf(w1[i]);
    } else if (i < T2) {
      int t = i - T1;
      int k = t / 384, n = t - k * 384;
      w2p[((size_t)(k >> 3) * 384 + n) * 8 + (k & 7)] = f2bf(w2[t]);
    } else if (i < T3) {
      int t = i - T2;
      int k = t / 384, n = t - k * 384;
      fpwp[((size_t)(k >> 3) * 384 + n) * 8 + (k & 7)] = f2bf(fpw[t]);
    } else if (i < T4) {
      int g = i - T3;
      rm1[g] = (g / 392) * 784 + idx1[g];
    } else {
      int g = i - T4;
      rm2[g] = (g / 392) * 784 + idx2[g];
    }
  }
}

// ---------------- K1: depthwise 7x7 conv + bias -> t (B,N,C) bf16 ----------------
__global__ __launch_bounds__(256) void dwconv_kernel(
    const float* __restrict__ x, const float* __restrict__ dww,
    const float* __restrict__ dwb, u16* __restrict__ t) {
  __shared__ __align__(16) u16 plane[8 * 34 * 40];  // 21760 B
  int tid = threadIdx.x;
  int b = blockIdx.y, c0 = blockIdx.x * 8;
  int ch = tid & 7, row = tid >> 3;
  int c = c0 + ch;

  float wg[49];
#pragma unroll
  for (int k2 = 0; k2 < 49; ++k2) wg[k2] = dww[c * 49 + k2];
  float bias = dwb[c];

  for (int q = tid; q < 1360; q += 256) {
    s16x8 z = {0, 0, 0, 0, 0, 0, 0, 0};
    *(s16x8*)(&plane[q * 8]) = z;
  }
  __syncthreads();
  for (int q = tid; q < 1568; q += 256) {
    int cc = q / 196, seg = q - cc * 196;
    int i = seg / 7, j4 = seg - i * 7;
    const float4 v = *(const float4*)(x + ((size_t)(b * 384 + c0 + cc)) * 784 +
                                      i * 28 + j4 * 4);
    s16x4 p;
    p[0] = (short)f2bf(v.x);
    p[1] = (short)f2bf(v.y);
    p[2] = (short)f2bf(v.z);
    p[3] = (short)f2bf(v.w);
    *(s16x4*)(&plane[cc * 1360 + (3 + i) * 40 + 4 + j4 * 4]) = p;
  }
  __syncthreads();

  if (row < 28) {
    float acc[28];
#pragma unroll
    for (int o = 0; o < 28; ++o) acc[o] = bias;
#pragma unroll
    for (int di = 0; di < 7; ++di) {
      const u16* base = &plane[ch * 1360 + (row + di) * 40];
      u32x4 ga = *(const u32x4*)(base);
      u32x4 gb = *(const u32x4*)(base + 8);
      u32x4 gc = *(const u32x4*)(base + 16);
      u32x4 gd = *(const u32x4*)(base + 24);
      u32x4 ge = *(const u32x4*)(base + 32);
      unsigned dw[20] = {ga[0], ga[1], ga[2], ga[3], gb[0], gb[1], gb[2],
                         gb[3], gc[0], gc[1], gc[2], gc[3], gd[0], gd[1],
                         gd[2], gd[3], ge[0], ge[1], ge[2], ge[3]};
      float v[35];
#pragma unroll
      for (int tt = 0; tt < 35; ++tt) {
        unsigned d = dw[tt >> 1];
        v[tt] = (tt & 1) ? __builtin_bit_cast(float, d & 0xFFFF0000u)
                         : __builtin_bit_cast(float, d << 16);
      }
#pragma unroll
      for (int o = 0; o < 28; ++o)
#pragma unroll
        for (int dj = 0; dj < 7; ++dj)
          acc[o] += v[o + 1 + dj] * wg[di * 7 + dj];
    }
    size_t obase = ((size_t)(b * 784 + row * 28)) * 384 + c;
#pragma unroll
    for (int o = 0; o < 28; ++o) t[obase + (size_t)o * 384] = f2bf(acc[o]);
  }
}

// ---------------- K2: gather + LayerNorm -> A1, A2 (bf16, MxK dense) ----------------
__global__ __launch_bounds__(256) void gatherln_kernel(
    const u16* __restrict__ t, const int* __restrict__ idx1,
    const int* __restrict__ idx2, const float* __restrict__ nw1,
    const float* __restrict__ nb1, const float* __restrict__ nw2,
    const float* __restrict__ nb2, u16* __restrict__ A1, u16* __restrict__ A2) {
  int wid = threadIdx.x >> 6, lane = threadIdx.x & 63;
  int g = blockIdx.x * 4 + wid;
  bool is1 = g < 50176;
  int gg = is1 ? g : g - 50176;
  const int* idx = is1 ? idx1 : idx2;
  int b = gg / 392;
  int jj = gg - b * 392;
  int ntok = idx[b * 392 + jj];
  const u16* src = t + ((size_t)(b * 784 + ntok)) * 384 + lane * 6;
  float v[6];
  u16x2 u0 = *(const u16x2*)(src);
  u16x2 u1 = *(const u16x2*)(src + 2);
  u16x2 u2 = *(const u16x2*)(src + 4);
  v[0] = bf2f(u0[0]); v[1] = bf2f(u0[1]);
  v[2] = bf2f(u1[0]); v[3] = bf2f(u1[1]);
  v[4] = bf2f(u2[0]); v[5] = bf2f(u2[1]);
  float s = 0.f, q = 0.f;
#pragma unroll
  for (int e = 0; e < 6; ++e) { s += v[e]; q += v[e] * v[e]; }
#pragma unroll
  for (int off = 32; off >= 1; off >>= 1) {
    s += __shfl_xor(s, off);
    q += __shfl_xor(q, off);
  }
  float mu = s * (1.f / 384.f);
  float var = q * (1.f / 384.f) - mu * mu;
  float rs = rsqrtf(var + 1e-6f);
  const float* nw = is1 ? nw1 : nw2;
  const float* nb = is1 ? nb1 : nb2;
  u16* dst = (is1 ? A1 : A2) + (size_t)gg * 384 + lane * 6;
  int k0 = lane * 6;
#pragma unroll
  for (int e = 0; e < 6; ++e)
    dst[e] = f2bf((v[e] - mu) * rs * nw[k0 + e] + nb[k0 + e]);
}

// ---------------- K3/K4/K5: bf16 MFMA GEMM, 128x128 tile, 4 waves ----------------
// A: M x K row-major bf16.  Wp: packed B, [k/8][n][8] bf16.
// Double-buffered LDS; stage(kt+1) issued BEFORE compute(kt) so the
// global_load_lds latency hides under ds_read+MFMA; one barrier per K-step.
// 1-D grid (divisible by 8) + bijective chunked XCD swizzle.
// EPI 0: out[m*N+col] = bf16(gelu(acc + bias[col]))
// EPI 1: out[rowmap[m]*384+col] = bf16((acc + bias[col]) * scale[col])
template <int EPI>
__global__ __launch_bounds__(256) void gemm_kernel(
    const u16* __restrict__ A, const u16* __restrict__ Wp,
    const float* __restrict__ bias, const float* __restrict__ scale,
    const int* __restrict__ rowmap, u16* __restrict__ out, int N, int K,
    int gx) {
  __shared__ __align__(16) u16 As[2][4096];  // [buf][kg 4][row 128][e 8]
  __shared__ __align__(16) u16 Bs[2][4096];  // [buf][kg 4][col 128][e 8]
  int tid = threadIdx.x;
  int wid = tid >> 6, lane = tid & 63;
  int wm = wid >> 1, wn = wid & 1;
  int nwg = gridDim.x;
  int bid = blockIdx.x;
  int wgid = (bid & 7) * (nwg >> 3) + (bid >> 3);
  int by = wgid / gx, bx = wgid - by * gx;
  int m_base = by * 128, n_base = bx * 128;
  const f32x4 vzero = {0.f, 0.f, 0.f, 0.f};
  f32x4 acc[4][4];
#pragma unroll
  for (int i = 0; i < 4; ++i)
#pragma unroll
    for (int j = 0; j < 4; ++j) acc[i][j] = vzero;
  int nk = K >> 5;

  auto stage = [&](int buf, int kt) {
#pragma unroll
    for (int it = 0; it < 2; ++it) {  // A: chunk p -> (kg,row); dest linear
      int p = wid * 128 + it * 64 + lane;
      int kg = p >> 7, row = p & 127;
      const u16* ga = A + (size_t)(m_base + row) * K + (kt << 5) + (kg << 3);
      gload_lds16(ga, &As[buf][(wid * 128 + it * 64) * 8]);
    }
#pragma unroll
    for (int it = 0; it < 2; ++it) {  // B: chunk p -> (kg,col); coalesced
      int p = wid * 128 + it * 64 + lane;
      int kg = p >> 7, col = p & 127;
      const u16* gb = Wp + ((size_t)((kt << 2) + kg) * N + n_base + col) * 8;
      gload_lds16(gb, &Bs[buf][(wid * 128 + it * 64) * 8]);
    }
  };

  stage(0, 0);
  __syncthreads();
  int cur = 0;
  for (int kt = 0; kt < nk; ++kt) {
    if (kt + 1 < nk) stage(cur ^ 1, kt + 1);
    int kg = lane >> 4, r = lane & 15;
    s16x8 af[4], bfr[4];
#pragma unroll
    for (int i = 0; i < 4; ++i)
      af[i] = *(const s16x8*)(&As[cur][(kg * 128 + wm * 64 + i * 16 + r) * 8]);
#pragma unroll
    for (int j = 0; j < 4; ++j)
      bfr[j] = *(const s16x8*)(&Bs[cur][(kg * 128 + wn * 64 + j * 16 + r) * 8]);
#pragma unroll
    for (int i = 0; i < 4; ++i)
#pragma unroll
      for (int j = 0; j < 4; ++j)
        acc[i][j] = mfma16x16x32(af[i], bfr[j], acc[i][j]);
    __syncthreads();
    cur ^= 1;
  }
  // epilogue: D row = (lane>>4)*4 + reg, col = lane&15
  int cl = lane & 15;
  int rg = (lane >> 4) * 4;
#pragma unroll
  for (int i = 0; i < 4; ++i) {
#pragma unroll
    for (int reg = 0; reg < 4; ++reg) {
      int m = m_base + wm * 64 + i * 16 + rg + reg;
      size_t rowoff;
      if (EPI == 0) rowoff = (size_t)m * N;
      else rowoff = (size_t)rowmap[m] * 384;
#pragma unroll
      for (int j = 0; j < 4; ++j) {
        int col = n_base + wn * 64 + j * 16 + cl;
        float v = acc[i][j][reg];
        v += bias[col];
        if (EPI == 0) v = 0.5f * v * (1.f + erff(v * 0.70710678118f));
        else v *= scale[col];
        out[rowoff + col] = f2bf(v);
      }
    }
  }
}

// ---------------- K6: un-transpose (B,N,C)->(B,C,N) + residual add ----------------
__global__ __launch_bounds__(256) void unscatter_add_kernel(
    const u16* __restrict__ U, const float* __restrict__ x,
    float* __restrict__ out) {
  __shared__ float tile[32][33];
  int b = blockIdx.y;
  int ct = blockIdx.x % 12, nt = blockIdx.x / 12;
  int c0 = ct * 32, n0 = nt * 32;
  int tid = threadIdx.x;
#pragma unroll
  for (int it = 0; it < 4; ++it) {
    int q = tid + it * 256;
    int nl = q >> 5, cl = q & 31;
    if (n0 + nl < 784)
      tile[nl][cl] = bf2f(U[((size_t)(b * 784 + n0 + nl)) * 384 + c0 + cl]);
  }
  __syncthreads();
#pragma unroll
  for (int it = 0; it < 4; ++it) {
    int q = tid + it * 256;
    int cl = q >> 5, nl = q & 31;
    int n = n0 + nl;
    if (n < 784) {
      size_t o = ((size_t)(b * 384 + c0 + cl)) * 784 + n;
      out[o] = x[o] + tile[nl][cl];
    }
  }
}

extern "C" void kernel_launch(void* const* d_in, const int* in_sizes, int n_in,
                              void* d_out, int out_size, void* d_ws,
                              size_t ws_size, hipStream_t stream) {
  const float* x = (const float*)d_in[0];
  const int* idx1 = (const int*)d_in[1];
  const int* idx2 = (const int*)d_in[2];
  const float* dww = (const float*)d_in[3];
  const float* dwb = (const float*)d_in[4];
  const float* nw = (const float*)d_in[5];
  const float* nb = (const float*)d_in[6];
  const float* w1 = (const float*)d_in[7];
  const float* b1 = (const float*)d_in[8];
  const float* w2 = (const float*)d_in[9];
  const float* b2 = (const float*)d_in[10];
  const float* gamma = (const float*)d_in[11];
  const float* fnw = (const float*)d_in[12];
  const float* fnb = (const float*)d_in[13];
  const float* fpw = (const float*)d_in[14];
  const float* fpb = (const float*)d_in[15];
  const float* fpg = (const float*)d_in[16];

  char* ws = (char*)d_ws;
  u16* H = (u16*)(ws);                     // 154,140,672 B (50176x1536)
  u16* t = (u16*)(ws);                     //  77,070,336 B (100352x384), aliases H
  u16* A1 = (u16*)(ws + 154140672);        //  38,535,168 B (50176x384)
  u16* A2 = (u16*)(ws + 192675840);        //  38,535,168 B
  u16* U = (u16*)(ws + 231211008);         //  77,070,336 B (100352x384)
  u16* w1p = (u16*)(ws + 308281344);       //   1,179,648 B
  u16* w2p = (u16*)(ws + 309460992);       //   1,179,648 B
  u16* fpwp = (u16*)(ws + 310640640);      //     294,912 B
  int* rm1 = (int*)(ws + 310935552);       //     200,704 B
  int* rm2 = (int*)(ws + 311136256);       //     200,704 B
  (void)ws_size; (void)in_sizes; (void)n_in; (void)out_size;

  pack_kernel<<<1024, 256, 0, stream>>>(w1, w2, fpw, idx1, idx2, w1p, w2p,
                                        fpwp, rm1, rm2);
  dwconv_kernel<<<dim3(48, 128), 256, 0, stream>>>(x, dww, dwb, t);
  gatherln_kernel<<<25088, 256, 0, stream>>>(t, idx1, idx2, nw, nb, fnw, fnb,
                                             A1, A2);
  gemm_kernel<0><<<4704, 256, 0, stream>>>(A1, w1p, b1, nullptr, nullptr, H,
                                           1536, 384, 12);
  gemm_kernel<1><<<1176, 256, 0, stream>>>(H, w2p, b2, gamma, rm1, U, 384,
                                           1536, 3);
  gemm_kernel<1><<<1176, 256, 0, stream>>>(A2, fpwp, fpb, fpg, rm2, U, 384,
                                           384, 3);
  unscatter_add_kernel<<<dim3(300, 128), 256, 0, stream>>>(U, x,
                                                           (float*)d_out);
}

// Round 5
// 508.698 us; speedup vs baseline: 1.0940x; 1.0141x over previous
//
#include <hip/hip_runtime.h>
#include <math.h>

typedef unsigned short u16;
typedef short s16x8 __attribute__((ext_vector_type(8)));
typedef short s16x4 __attribute__((ext_vector_type(4)));
typedef unsigned int u32x4 __attribute__((ext_vector_type(4)));
typedef __bf16 bf16x8 __attribute__((ext_vector_type(8)));
typedef float f32x4 __attribute__((ext_vector_type(4)));
typedef unsigned short u16x2 __attribute__((ext_vector_type(2)));

__device__ __forceinline__ float bf2f(u16 u) {
  unsigned x = ((unsigned)u) << 16;
  return __builtin_bit_cast(float, x);
}
__device__ __forceinline__ u16 f2bf(float f) {
  unsigned x = __builtin_bit_cast(unsigned, f);
  unsigned r = (x + 0x7FFFu + ((x >> 16) & 1u)) >> 16;
  return (u16)r;
}

// ---- MFMA wrapper robust to builtin signature (short8 vs bf16x8) ----
template <typename T>
__device__ __forceinline__ auto mfma_try(T a, T b, f32x4 c, int)
    -> decltype(__builtin_amdgcn_mfma_f32_16x16x32_bf16(a, b, c, 0, 0, 0)) {
  return __builtin_amdgcn_mfma_f32_16x16x32_bf16(a, b, c, 0, 0, 0);
}
template <typename T>
__device__ __forceinline__ f32x4 mfma_try(T a, T b, f32x4 c, long) {
  return __builtin_amdgcn_mfma_f32_16x16x32_bf16(
      __builtin_bit_cast(bf16x8, a), __builtin_bit_cast(bf16x8, b), c, 0, 0, 0);
}
__device__ __forceinline__ f32x4 mfma16x16x32(s16x8 a, s16x8 b, f32x4 c) {
  return mfma_try(a, b, c, 0);
}

// ---- async global->LDS, 16B per lane, wave-uniform LDS base + lane*16 ----
__device__ __forceinline__ void gload_lds16(const u16* g, u16* l) {
  __builtin_amdgcn_global_load_lds(
      (__attribute__((address_space(1))) void*)(u16*)g,
      (__attribute__((address_space(3))) void*)l, 16, 0, 0);
}

// ---------------- K0: pack weights to bf16 [k/8][n][8], build rowmaps ----------------
__global__ __launch_bounds__(256) void pack_kernel(
    const float* __restrict__ w1, const float* __restrict__ w2,
    const float* __restrict__ fpw, const int* __restrict__ idx1,
    const int* __restrict__ idx2, u16* __restrict__ w1p, u16* __restrict__ w2p,
    u16* __restrict__ fpwp, int* __restrict__ rm1, int* __restrict__ rm2) {
  const int T1 = 589824;           // w1 (384x1536)
  const int T2 = T1 + 589824;      // w2 (1536x384)
  const int T3 = T2 + 147456;      // fp_w (384x384)
  const int T4 = T3 + 50176;       // rowmap1
  const int T5 = T4 + 50176;       // rowmap2
  int stride = gridDim.x * 256;
  for (int i = blockIdx.x * 256 + threadIdx.x; i < T5; i += stride) {
    if (i < T1) {
      int k = i / 1536, n = i - k * 1536;
      w1p[((size_t)(k >> 3) * 1536 + n) * 8 + (k & 7)] = f2bf(w1[i]);
    } else if (i < T2) {
      int t = i - T1;
      int k = t / 384, n = t - k * 384;
      w2p[((size_t)(k >> 3) * 384 + n) * 8 + (k & 7)] = f2bf(w2[t]);
    } else if (i < T3) {
      int t = i - T2;
      int k = t / 384, n = t - k * 384;
      fpwp[((size_t)(k >> 3) * 384 + n) * 8 + (k & 7)] = f2bf(fpw[t]);
    } else if (i < T4) {
      int g = i - T3;
      rm1[g] = (g / 392) * 784 + idx1[g];
    } else {
      int g = i - T4;
      rm2[g] = (g / 392) * 784 + idx2[g];
    }
  }
}

// ---------------- K1: depthwise 7x7 conv + bias -> t (B,N,C) bf16 ----------------
// 8-output chunks: acc[8] + 16-value window (2 aligned ds_read_b128) keeps
// live set ~100 VGPR (previous acc[28]/v[35]/wg[49] spilled to scratch).
__global__ __launch_bounds__(256) void dwconv_kernel(
    const float* __restrict__ x, const float* __restrict__ dww,
    const float* __restrict__ dwb, u16* __restrict__ t) {
  __shared__ __align__(16) u16 plane[8 * 34 * 40];  // 21760 B
  int tid = threadIdx.x;
  int b = blockIdx.y, c0 = blockIdx.x * 8;
  int ch = tid & 7, row = tid >> 3;
  int c = c0 + ch;

  float wg[49];
#pragma unroll
  for (int k2 = 0; k2 < 49; ++k2) wg[k2] = dww[c * 49 + k2];
  float bias = dwb[c];

  for (int q = tid; q < 1360; q += 256) {
    s16x8 z = {0, 0, 0, 0, 0, 0, 0, 0};
    *(s16x8*)(&plane[q * 8]) = z;
  }
  __syncthreads();
  for (int q = tid; q < 1568; q += 256) {
    int cc = q / 196, seg = q - cc * 196;
    int i = seg / 7, j4 = seg - i * 7;
    const float4 v = *(const float4*)(x + ((size_t)(b * 384 + c0 + cc)) * 784 +
                                      i * 28 + j4 * 4);
    s16x4 p;
    p[0] = (short)f2bf(v.x);
    p[1] = (short)f2bf(v.y);
    p[2] = (short)f2bf(v.z);
    p[3] = (short)f2bf(v.w);
    *(s16x4*)(&plane[cc * 1360 + (3 + i) * 40 + 4 + j4 * 4]) = p;
  }
  __syncthreads();

  if (row < 28) {
    size_t obase = ((size_t)(b * 784 + row * 28)) * 384 + c;
#pragma unroll
    for (int ck = 0; ck < 4; ++ck) {
      float acc[8];
#pragma unroll
      for (int o = 0; o < 8; ++o) acc[o] = bias;
#pragma unroll
      for (int di = 0; di < 7; ++di) {
        // window covers plane cols ck*8 .. ck*8+15; outputs need +1..+14
        const u16* base2 = &plane[ch * 1360 + (row + di) * 40 + ck * 8];
        u32x4 ga = *(const u32x4*)(base2);
        u32x4 gb = *(const u32x4*)(base2 + 8);
        unsigned dw[8] = {ga[0], ga[1], ga[2], ga[3],
                          gb[0], gb[1], gb[2], gb[3]};
        float v[16];
#pragma unroll
        for (int tt = 0; tt < 16; ++tt) {
          unsigned d = dw[tt >> 1];
          v[tt] = (tt & 1) ? __builtin_bit_cast(float, d & 0xFFFF0000u)
                           : __builtin_bit_cast(float, d << 16);
        }
#pragma unroll
        for (int o = 0; o < 8; ++o)
#pragma unroll
          for (int dj = 0; dj < 7; ++dj)
            acc[o] += v[o + dj + 1] * wg[di * 7 + dj];
      }
      int lim = (ck == 3) ? 4 : 8;
#pragma unroll
      for (int o = 0; o < 8; ++o)
        if (o < lim) t[obase + (size_t)(ck * 8 + o) * 384] = f2bf(acc[o]);
    }
  }
}

// ---------------- K2: gather + LayerNorm -> A1, A2 (bf16, MxK dense) ----------------
__global__ __launch_bounds__(256) void gatherln_kernel(
    const u16* __restrict__ t, const int* __restrict__ idx1,
    const int* __restrict__ idx2, const float* __restrict__ nw1,
    const float* __restrict__ nb1, const float* __restrict__ nw2,
    const float* __restrict__ nb2, u16* __restrict__ A1, u16* __restrict__ A2) {
  int wid = threadIdx.x >> 6, lane = threadIdx.x & 63;
  int g = blockIdx.x * 4 + wid;
  bool is1 = g < 50176;
  int gg = is1 ? g : g - 50176;
  const int* idx = is1 ? idx1 : idx2;
  int b = gg / 392;
  int jj = gg - b * 392;
  int ntok = idx[b * 392 + jj];
  const u16* src = t + ((size_t)(b * 784 + ntok)) * 384 + lane * 6;
  float v[6];
  u16x2 u0 = *(const u16x2*)(src);
  u16x2 u1 = *(const u16x2*)(src + 2);
  u16x2 u2 = *(const u16x2*)(src + 4);
  v[0] = bf2f(u0[0]); v[1] = bf2f(u0[1]);
  v[2] = bf2f(u1[0]); v[3] = bf2f(u1[1]);
  v[4] = bf2f(u2[0]); v[5] = bf2f(u2[1]);
  float s = 0.f, q = 0.f;
#pragma unroll
  for (int e = 0; e < 6; ++e) { s += v[e]; q += v[e] * v[e]; }
#pragma unroll
  for (int off = 32; off >= 1; off >>= 1) {
    s += __shfl_xor(s, off);
    q += __shfl_xor(q, off);
  }
  float mu = s * (1.f / 384.f);
  float var = q * (1.f / 384.f) - mu * mu;
  float rs = rsqrtf(var + 1e-6f);
  const float* nw = is1 ? nw1 : nw2;
  const float* nb = is1 ? nb1 : nb2;
  u16* dst = (is1 ? A1 : A2) + (size_t)gg * 384 + lane * 6;
  int k0 = lane * 6;
#pragma unroll
  for (int e = 0; e < 6; ++e)
    dst[e] = f2bf((v[e] - mu) * rs * nw[k0 + e] + nb[k0 + e]);
}

// ---------------- K3/K4/K5: bf16 MFMA GEMM, 128x128 tile, 4 waves ----------------
// A: M x K bf16, row-major (APK=0) or octet-packed [k/8][m][8] (APK=1).
// Wp: packed B, [k/8][n][8] bf16.  Double-buffered LDS; stage(kt+1) before
// compute(kt); one barrier per K-step; bijective chunked XCD swizzle.
// EPI 0: H[(col/8)*M + m][col%8] = bf16(gelu_sig(acc + bias[col]))  (packed out)
// EPI 1: out[rowmap[m]*384+col] = bf16((acc + bias[col]) * scale[col])
template <int EPI, int APK>
__global__ __launch_bounds__(256) void gemm_kernel(
    const u16* __restrict__ A, const u16* __restrict__ Wp,
    const float* __restrict__ bias, const float* __restrict__ scale,
    const int* __restrict__ rowmap, u16* __restrict__ out, int N, int K,
    int gx, int M) {
  __shared__ __align__(16) u16 As[2][4096];  // [buf][kg 4][row 128][e 8]
  __shared__ __align__(16) u16 Bs[2][4096];  // [buf][kg 4][col 128][e 8]
  int tid = threadIdx.x;
  int wid = tid >> 6, lane = tid & 63;
  int wm = wid >> 1, wn = wid & 1;
  int nwg = gridDim.x;
  int bid = blockIdx.x;
  int wgid = (bid & 7) * (nwg >> 3) + (bid >> 3);
  int by = wgid / gx, bx = wgid - by * gx;
  int m_base = by * 128, n_base = bx * 128;
  const f32x4 vzero = {0.f, 0.f, 0.f, 0.f};
  f32x4 acc[4][4];
#pragma unroll
  for (int i = 0; i < 4; ++i)
#pragma unroll
    for (int j = 0; j < 4; ++j) acc[i][j] = vzero;
  int nk = K >> 5;

  auto stage = [&](int buf, int kt) {
#pragma unroll
    for (int it = 0; it < 2; ++it) {  // A: chunk p -> (kg,row); dest linear
      int p = wid * 128 + it * 64 + lane;
      int kg = p >> 7, row = p & 127;
      const u16* ga;
      if (APK)
        ga = A + ((size_t)((kt << 2) + kg) * M + m_base + row) * 8;
      else
        ga = A + (size_t)(m_base + row) * K + (kt << 5) + (kg << 3);
      gload_lds16(ga, &As[buf][(wid * 128 + it * 64) * 8]);
    }
#pragma unroll
    for (int it = 0; it < 2; ++it) {  // B: chunk p -> (kg,col); coalesced
      int p = wid * 128 + it * 64 + lane;
      int kg = p >> 7, col = p & 127;
      const u16* gb = Wp + ((size_t)((kt << 2) + kg) * N + n_base + col) * 8;
      gload_lds16(gb, &Bs[buf][(wid * 128 + it * 64) * 8]);
    }
  };

  stage(0, 0);
  __syncthreads();
  int cur = 0;
  for (int kt = 0; kt < nk; ++kt) {
    if (kt + 1 < nk) stage(cur ^ 1, kt + 1);
    int kg = lane >> 4, r = lane & 15;
    s16x8 af[4], bfr[4];
#pragma unroll
    for (int i = 0; i < 4; ++i)
      af[i] = *(const s16x8*)(&As[cur][(kg * 128 + wm * 64 + i * 16 + r) * 8]);
#pragma unroll
    for (int j = 0; j < 4; ++j)
      bfr[j] = *(const s16x8*)(&Bs[cur][(kg * 128 + wn * 64 + j * 16 + r) * 8]);
#pragma unroll
    for (int i = 0; i < 4; ++i)
#pragma unroll
      for (int j = 0; j < 4; ++j)
        acc[i][j] = mfma16x16x32(af[i], bfr[j], acc[i][j]);
    __syncthreads();
    cur ^= 1;
  }
  // epilogue: D row = (lane>>4)*4 + reg, col = lane&15
  int cl = lane & 15;
  int rg = (lane >> 4) * 4;
#pragma unroll
  for (int i = 0; i < 4; ++i) {
#pragma unroll
    for (int reg = 0; reg < 4; ++reg) {
      int m = m_base + wm * 64 + i * 16 + rg + reg;
      size_t rowoff = 0;
      if (EPI == 1) rowoff = (size_t)rowmap[m] * 384;
#pragma unroll
      for (int j = 0; j < 4; ++j) {
        int col = n_base + wn * 64 + j * 16 + cl;
        float v = acc[i][j][reg];
        v += bias[col];
        if (EPI == 0) {
          v = v / (1.f + __expf(-1.702f * v));  // sigmoid-GELU (gamma-damped)
          out[((size_t)(col >> 3) * M + m) * 8 + (col & 7)] = f2bf(v);
        } else {
          v *= scale[col];
          out[rowoff + col] = f2bf(v);
        }
      }
    }
  }
}

// ---------------- K6: un-transpose (B,N,C)->(B,C,N) + residual add ----------------
__global__ __launch_bounds__(256) void unscatter_add_kernel(
    const u16* __restrict__ U, const float* __restrict__ x,
    float* __restrict__ out) {
  __shared__ float tile[32][33];
  int b = blockIdx.y;
  int ct = blockIdx.x % 12, nt = blockIdx.x / 12;
  int c0 = ct * 32, n0 = nt * 32;
  int tid = threadIdx.x;
#pragma unroll
  for (int it = 0; it < 4; ++it) {
    int q = tid + it * 256;
    int nl = q >> 5, cl = q & 31;
    if (n0 + nl < 784)
      tile[nl][cl] = bf2f(U[((size_t)(b * 784 + n0 + nl)) * 384 + c0 + cl]);
  }
  __syncthreads();
#pragma unroll
  for (int it = 0; it < 4; ++it) {
    int q = tid + it * 256;
    int cl = q >> 5, nl = q & 31;
    int n = n0 + nl;
    if (n < 784) {
      size_t o = ((size_t)(b * 384 + c0 + cl)) * 784 + n;
      out[o] = x[o] + tile[nl][cl];
    }
  }
}

extern "C" void kernel_launch(void* const* d_in, const int* in_sizes, int n_in,
                              void* d_out, int out_size, void* d_ws,
                              size_t ws_size, hipStream_t stream) {
  const float* x = (const float*)d_in[0];
  const int* idx1 = (const int*)d_in[1];
  const int* idx2 = (const int*)d_in[2];
  const float* dww = (const float*)d_in[3];
  const float* dwb = (const float*)d_in[4];
  const float* nw = (const float*)d_in[5];
  const float* nb = (const float*)d_in[6];
  const float* w1 = (const float*)d_in[7];
  const float* b1 = (const float*)d_in[8];
  const float* w2 = (const float*)d_in[9];
  const float* b2 = (const float*)d_in[10];
  const float* gamma = (const float*)d_in[11];
  const float* fnw = (const float*)d_in[12];
  const float* fnb = (const float*)d_in[13];
  const float* fpw = (const float*)d_in[14];
  const float* fpb = (const float*)d_in[15];
  const float* fpg = (const float*)d_in[16];

  char* ws = (char*)d_ws;
  u16* H = (u16*)(ws);                     // 154,140,672 B (50176x1536, packed)
  u16* t = (u16*)(ws);                     //  77,070,336 B (100352x384), aliases H
  u16* A1 = (u16*)(ws + 154140672);        //  38,535,168 B (50176x384)
  u16* A2 = (u16*)(ws + 192675840);        //  38,535,168 B
  u16* U = (u16*)(ws + 231211008);         //  77,070,336 B (100352x384)
  u16* w1p = (u16*)(ws + 308281344);       //   1,179,648 B
  u16* w2p = (u16*)(ws + 309460992);       //   1,179,648 B
  u16* fpwp = (u16*)(ws + 310640640);      //     294,912 B
  int* rm1 = (int*)(ws + 310935552);       //     200,704 B
  int* rm2 = (int*)(ws + 311136256);       //     200,704 B
  (void)ws_size; (void)in_sizes; (void)n_in; (void)out_size;

  pack_kernel<<<1024, 256, 0, stream>>>(w1, w2, fpw, idx1, idx2, w1p, w2p,
                                        fpwp, rm1, rm2);
  dwconv_kernel<<<dim3(48, 128), 256, 0, stream>>>(x, dww, dwb, t);
  gatherln_kernel<<<25088, 256, 0, stream>>>(t, idx1, idx2, nw, nb, fnw, fnb,
                                             A1, A2);
  gemm_kernel<0, 0><<<4704, 256, 0, stream>>>(A1, w1p, b1, nullptr, nullptr, H,
                                              1536, 384, 12, 50176);
  gemm_kernel<1, 1><<<1176, 256, 0, stream>>>(H, w2p, b2, gamma, rm1, U, 384,
                                              1536, 3, 50176);
  gemm_kernel<1, 0><<<1176, 256, 0, stream>>>(A2, fpwp, fpb, fpg, rm2, U, 384,
                                              384, 3, 50176);
  unscatter_add_kernel<<<dim3(300, 128), 256, 0, stream>>>(U, x,
                                                           (float*)d_out);
}